// Round 9
// baseline (104.530 us; speedup 1.0000x reference)
//
#include <hip/hip_runtime.h>

// BuildCombinationsDim2: out[b,t,j] = x[b,t, idx[j]] where idx is the
// flattened list of k=2 combinations of F=32 features (lexicographic).
// ncr = 2*C(32,2) = 992. Pure gather along last axis; write-BW-bound.
// R9: R4's best structure (LDS-staged, 16 rows/block, 8192 blocks) with
// PLAIN stores — single-variable A/B vs nt. The 6.9 TB/s fill kernel
// uses plain stores; L2 write-allocate + full-line writeback may beat
// the nt bypass path for full-line streaming writes.

#define FDIM 32
#define NCR 992            // k * C(F,2)
#define G_PER_ROW 248      // NCR / 4 float4 groups per row
#define ROWS_PER_BLOCK 16
#define BLOCK 256

typedef float f32x4 __attribute__((ext_vector_type(4)));
typedef float f32x2 __attribute__((ext_vector_type(2)));

__global__ __launch_bounds__(BLOCK)
void comb_gather_kernel(const float* __restrict__ x,
                        float* __restrict__ out,
                        int nrows) {
    __shared__ float lds[ROWS_PER_BLOCK * FDIM];   // 16 rows * 32 f32 = 2 KB

    const int tid  = threadIdx.x;
    const int row0 = blockIdx.x * ROWS_PER_BLOCK;
    const bool full = (row0 + ROWS_PER_BLOCK) <= nrows;

    // Stage 16 input rows (512 floats = 256 float2) into LDS, coalesced.
    {
        const f32x2* src = reinterpret_cast<const f32x2*>(x + (size_t)row0 * FDIM);
        if (full) {
            reinterpret_cast<f32x2*>(lds)[tid] = src[tid];
        } else {
            int row_of_load = row0 + (tid * 2) / FDIM;
            if (row_of_load < nrows)
                reinterpret_cast<f32x2*>(lds)[tid] = src[tid];
        }
    }

    // Thread g owns output float4 group g: columns j = 4g..4g+3.
    // j -> combination c = 2g + (u>>1), position j&1. Closed-form
    // inversion of start(i) = i*(63-i)/2 with +-1 integer fixup.
    int feat[4];
    const int g = tid;
    if (g < G_PER_ROW) {
        const int c0 = 2 * g;
        float s = sqrtf(3969.0f - 8.0f * (float)c0);
        int i0 = (int)((63.0f - s) * 0.5f);
        if (i0 < 0) i0 = 0;
        int st0  = (i0 * (63 - i0)) >> 1;
        int stn0 = ((i0 + 1) * (62 - i0)) >> 1;
        if (stn0 <= c0) { i0++; st0 = stn0; stn0 = ((i0 + 1) * (62 - i0)) >> 1; }
        else if (st0 > c0) { i0--; stn0 = st0; st0 = (i0 * (63 - i0)) >> 1; }
        feat[0] = i0;
        feat[1] = c0 - st0 + i0 + 1;
        const int c1 = c0 + 1;
        int i1 = i0, st1 = st0;
        if (stn0 <= c1) { i1 = i0 + 1; st1 = stn0; }
        feat[2] = i1;
        feat[3] = c1 - st1 + i1 + 1;
    }
    __syncthreads();

    if (g >= G_PER_ROW) return;

    if (full) {
        f32x4* outp = reinterpret_cast<f32x4*>(out + (size_t)row0 * NCR) + g;
        #pragma unroll
        for (int r = 0; r < ROWS_PER_BLOCK; ++r) {
            const float* rowp = lds + r * FDIM;   // same row across lanes
            f32x4 v;
            v.x = rowp[feat[0]];
            v.y = rowp[feat[1]];
            v.z = rowp[feat[2]];
            v.w = rowp[feat[3]];
            *outp = v;                            // PLAIN store (A/B vs nt)
            outp += NCR / 4;
        }
    } else {
        #pragma unroll
        for (int r = 0; r < ROWS_PER_BLOCK; ++r) {
            int row = row0 + r;
            if (row >= nrows) break;
            const float* rowp = lds + r * FDIM;
            f32x4 v;
            v.x = rowp[feat[0]];
            v.y = rowp[feat[1]];
            v.z = rowp[feat[2]];
            v.w = rowp[feat[3]];
            *(reinterpret_cast<f32x4*>(out + (size_t)row * NCR) + g) = v;
        }
    }
}

extern "C" void kernel_launch(void* const* d_in, const int* in_sizes, int n_in,
                              void* d_out, int out_size, void* d_ws, size_t ws_size,
                              hipStream_t stream) {
    const float* x  = (const float*)d_in[0];
    float* out      = (float*)d_out;
    int nrows = in_sizes[0] / FDIM;                       // 32*4096 = 131072
    int grid  = (nrows + ROWS_PER_BLOCK - 1) / ROWS_PER_BLOCK;  // 8192
    hipLaunchKernelGGL(comb_gather_kernel, dim3(grid), dim3(BLOCK), 0, stream,
                       x, out, nrows);
}